// Round 5
// baseline (285.102 us; speedup 1.0000x reference)
//
#include <hip/hip_runtime.h>
#include <stdint.h>

// BS=2, QLEN=2048, DIM=1024, NH=16, HD=64
#define BSZ  2
#define SEQ  2048
#define DIM  1024
#define NHD  16
#define HD   64
#define MTOT (BSZ*SEQ)   // 4096

using short8  = __attribute__((ext_vector_type(8))) short;   // 8 bf16
using floatx4 = __attribute__((ext_vector_type(4))) float;   // MFMA C/D

#define QSCALE 0.18033688011112042f   // 0.125 * log2(e): softmax in exp2 domain
#define BIGM   1.44e30f               // mask penalty in exp2 domain

__device__ __forceinline__ unsigned short f2bf(float f) {
    unsigned int u = __float_as_uint(f);
    u += 0x7fffu + ((u >> 16) & 1u);     // RNE
    return (unsigned short)(u >> 16);
}
// pack 2 floats -> 2 bf16 (round-half-up) in 3 VALU ops via v_perm_b32
__device__ __forceinline__ unsigned int pk2r(float a, float b) {
    unsigned int ua = __float_as_uint(a) + 0x8000u;
    unsigned int ub = __float_as_uint(b) + 0x8000u;
    return __builtin_amdgcn_perm(ub, ua, 0x07060302);   // {ua_hi16, ub_hi16}
}

// async global->LDS, 16B per lane; dest is wave-uniform base + lane*16.
__device__ __forceinline__ void gll16(const void* g, const void* lds) {
    unsigned int loff = (unsigned int)(unsigned long long)lds;
    __builtin_amdgcn_global_load_lds(
        (const __attribute__((address_space(1))) unsigned int*)g,
        (__attribute__((address_space(3))) unsigned int*)loff, 16, 0, 0);
}

// ---------------------------------------------------------------------------
// fp32 -> bf16 bulk convert (X)
// ---------------------------------------------------------------------------
__global__ __launch_bounds__(256)
void conv_x(const float* __restrict__ X, unsigned short* __restrict__ Xbf) {
    size_t i = ((size_t)blockIdx.x * 256 + threadIdx.x) * 8;
    float4 a = *(const float4*)(X + i);
    float4 b = *(const float4*)(X + i + 4);
    uint4 u = {pk2r(a.x, a.y), pk2r(a.z, a.w), pk2r(b.x, b.y), pk2r(b.z, b.w)};
    *(uint4*)(Xbf + i) = u;
}

// ---------------------------------------------------------------------------
// W[k][n] fp32 -> Wt[n][k] bf16  (transpose + convert), 64x64 tiles
// ---------------------------------------------------------------------------
__global__ __launch_bounds__(256)
void conv_wt(const float* __restrict__ Wq, const float* __restrict__ Wk,
             const float* __restrict__ Wv, const float* __restrict__ Wo,
             unsigned short* __restrict__ Wt3, unsigned short* __restrict__ Wto)
{
    __shared__ float tile[64 * 65];
    const int z = blockIdx.z;
    const float* W = (z == 0) ? Wq : (z == 1) ? Wk : (z == 2) ? Wv : Wo;
    unsigned short* out = (z < 3) ? (Wt3 + (size_t)z * DIM * DIM) : Wto;
    const int k0 = blockIdx.x * 64, n0 = blockIdx.y * 64;
    const int t = threadIdx.x;
    const int r = t >> 2, c0 = (t & 3) * 16;
#pragma unroll
    for (int j = 0; j < 4; ++j) {
        float4 v = *(const float4*)&W[(size_t)(k0 + r) * DIM + n0 + c0 + j * 4];
        tile[r * 65 + c0 + j * 4 + 0] = v.x;
        tile[r * 65 + c0 + j * 4 + 1] = v.y;
        tile[r * 65 + c0 + j * 4 + 2] = v.z;
        tile[r * 65 + c0 + j * 4 + 3] = v.w;
    }
    __syncthreads();
    unsigned int p[8];
#pragma unroll
    for (int j = 0; j < 8; ++j)
        p[j] = pk2r(tile[(c0 + 2 * j) * 65 + r], tile[(c0 + 2 * j + 1) * 65 + r]);
    uint4 u0 = {p[0], p[1], p[2], p[3]}, u1 = {p[4], p[5], p[6], p[7]};
    unsigned short* dst = out + (size_t)(n0 + r) * DIM + k0 + c0;
    *(uint4*)dst = u0;
    *(uint4*)(dst + 8) = u1;
}

// ---------------------------------------------------------------------------
// QKV GEMM (m97-style 128x128, BK=32, global_load_lds).  Epilogue:
//   Q -> Qb[bh][s][d]   (scaled by QSCALE)
//   K -> Kb[bh][s][d]   (plain)
//   V -> VbT[bh][d][s]  (transposed, plain)
// ---------------------------------------------------------------------------
__global__ __launch_bounds__(256)
void qkv_gemm(const unsigned short* __restrict__ Xbf,
              const unsigned short* __restrict__ Wt3,
              const float* __restrict__ bq, const float* __restrict__ bk,
              const float* __restrict__ bv,
              unsigned short* __restrict__ Qb,
              unsigned short* __restrict__ Kb,
              unsigned short* __restrict__ VbT)
{
    __shared__ unsigned short As[128 * 32];
    __shared__ unsigned short Bs[128 * 32];

    const int t = threadIdx.x, w = t >> 6, lane = t & 63;
    const int lm = lane & 15, grp = lane >> 4;
    const int wm = w >> 1, wn = w & 1;
    const int m0 = blockIdx.x * 128;
    const int mat = blockIdx.y >> 3;             // 0=Q 1=K 2=V
    const int n0 = (blockIdx.y & 7) * 128;
    const unsigned short* Bg = Wt3 + (size_t)mat * DIM * DIM;

    const int lr = lane >> 2, lc = (lane & 3) * 8;

    floatx4 acc[4][4];
#pragma unroll
    for (int i = 0; i < 4; ++i)
#pragma unroll
        for (int j = 0; j < 4; ++j) acc[i][j] = (floatx4){0.f, 0.f, 0.f, 0.f};

    for (int kt = 0; kt < DIM / 32; ++kt) {
        const int k0 = kt * 32;
        const int r0 = w * 16;
        gll16(Xbf + (size_t)(m0 + r0 + lr) * DIM + k0 + lc,      &As[r0 * 32]);
        gll16(Xbf + (size_t)(m0 + 64 + r0 + lr) * DIM + k0 + lc, &As[(64 + r0) * 32]);
        gll16(Bg  + (size_t)(n0 + r0 + lr) * DIM + k0 + lc,      &Bs[r0 * 32]);
        gll16(Bg  + (size_t)(n0 + 64 + r0 + lr) * DIM + k0 + lc, &Bs[(64 + r0) * 32]);
        __syncthreads();
        short8 af[4], bf[4];
#pragma unroll
        for (int mt = 0; mt < 4; ++mt)
            af[mt] = *(const short8*)&As[(wm * 64 + mt * 16 + lm) * 32 + grp * 8];
#pragma unroll
        for (int nt = 0; nt < 4; ++nt)
            bf[nt] = *(const short8*)&Bs[(wn * 64 + nt * 16 + lm) * 32 + grp * 8];
#pragma unroll
        for (int mt = 0; mt < 4; ++mt)
#pragma unroll
            for (int nt = 0; nt < 4; ++nt)
                acc[mt][nt] = __builtin_amdgcn_mfma_f32_16x16x32_bf16(af[mt], bf[nt], acc[mt][nt], 0, 0, 0);
        __syncthreads();
    }

    if (mat == 2) {          // V -> VbT[bh][d][s], 4 s-values packed
#pragma unroll
        for (int nt = 0; nt < 4; ++nt) {
            const int c = n0 + wn * 64 + nt * 16 + lm;
            const float bb = bv[c];
            const int h = c >> 6, d = c & 63;
#pragma unroll
            for (int mt = 0; mt < 4; ++mt) {
                const int r = m0 + wm * 64 + mt * 16 + grp * 4;
                const int b = r >> 11, s = r & 2047;
                uint2 pv;
                pv.x = pk2r(acc[mt][nt][0] + bb, acc[mt][nt][1] + bb);
                pv.y = pk2r(acc[mt][nt][2] + bb, acc[mt][nt][3] + bb);
                *(uint2*)&VbT[(((size_t)(b * NHD + h)) * HD + d) * SEQ + s] = pv;
            }
        }
    } else if (mat == 1) {   // K -> Kb[bh][s][d]
#pragma unroll
        for (int nt = 0; nt < 4; ++nt) {
            const int c = n0 + wn * 64 + nt * 16 + lm;
            const float bb = bk[c];
            const int h = c >> 6, d = c & 63;
#pragma unroll
            for (int mt = 0; mt < 4; ++mt)
#pragma unroll
                for (int reg = 0; reg < 4; ++reg) {
                    const int r = m0 + wm * 64 + mt * 16 + grp * 4 + reg;
                    const int b = r >> 11, s = r & 2047;
                    Kb[(((size_t)(b * NHD + h)) * SEQ + s) * HD + d] =
                        f2bf(acc[mt][nt][reg] + bb);
                }
        }
    } else {                 // Q -> Qb[bh][s][d] scaled
#pragma unroll
        for (int nt = 0; nt < 4; ++nt) {
            const int c = n0 + wn * 64 + nt * 16 + lm;
            const float bb = bq[c];
            const int h = c >> 6, d = c & 63;
#pragma unroll
            for (int mt = 0; mt < 4; ++mt)
#pragma unroll
                for (int reg = 0; reg < 4; ++reg) {
                    const int r = m0 + wm * 64 + mt * 16 + grp * 4 + reg;
                    const int b = r >> 11, s = r & 2047;
                    Qb[(((size_t)(b * NHD + h)) * SEQ + s) * HD + d] =
                        f2bf((acc[mt][nt][reg] + bb) * QSCALE);
                }
        }
    }
}

// ---------------------------------------------------------------------------
// Flash attention v5 — BARRIER-FREE K-loop.
// Block = 64 q-rows x one bh, 4 waves.  Each wave computes ALL 64 q over a
// DISJOINT 512-key range, reading K/V fragments directly global->VGPR
// (L2-served; K+V per bh = 512 KB).  Only in-loop LDS: wave-private P tile.
// Fixed-max exp2 softmax => key-partials of O and l are linear; one LDS
// exchange (2 barriers, post-loop) reduces the 4 wave partials.
// ---------------------------------------------------------------------------
__global__ __launch_bounds__(256)
void attn(const unsigned short* __restrict__ Qb,
          const unsigned short* __restrict__ Kb,
          const unsigned short* __restrict__ VbT,
          const float* __restrict__ mask,
          unsigned short* __restrict__ Cb)
{
    __shared__ union {
        unsigned short Ps[4][64 * 72];                     // in-loop P tiles
        struct { float Oex[12][16 * 66]; float Lex[4][64]; } ep;  // epilogue
    } sm;

    const int t = threadIdx.x, w = t >> 6, lane = t & 63;
    const int lm = lane & 15, grp = lane >> 4;
    const int bh = blockIdx.y, b = bh >> 4, h = bh & 15;
    const int q0 = blockIdx.x * 64;

    // Q B-frags for 4 q-subtiles (n = q = qt*16+lm, k = d)
    short8 qf[4][2];
#pragma unroll
    for (int qt = 0; qt < 4; ++qt) {
        const unsigned short* qrow = Qb + ((size_t)bh * SEQ + q0 + qt * 16 + lm) * HD;
        qf[qt][0] = *(const short8*)(qrow + grp * 8);
        qf[qt][1] = *(const short8*)(qrow + 32 + grp * 8);
    }

    floatx4 oacc[4][4];
#pragma unroll
    for (int i = 0; i < 4; ++i)
#pragma unroll
        for (int j = 0; j < 4; ++j) oacc[i][j] = (floatx4){0.f, 0.f, 0.f, 0.f};
    float lpart[4] = {0.f, 0.f, 0.f, 0.f};

    const unsigned short* Kg = Kb + (size_t)bh * SEQ * HD;
    const unsigned short* Vg = VbT + (size_t)bh * HD * SEQ;
    const float* maskb = mask + b * SEQ;
    unsigned short* Pw = sm.Ps[w];

    for (int kt = 0; kt < 8; ++kt) {
        const int kb = w * 512 + kt * 64;    // this wave's key-tile base

        // K A-frags (m = key = cg*16+lm, k = d) and V B-frags
        // (n = d = dg*16+lm, k = key) straight from global (L2)
        short8 kf[4][2], vf[4][2];
#pragma unroll
        for (int cg = 0; cg < 4; ++cg) {
            const unsigned short* kr = Kg + (size_t)(kb + cg * 16 + lm) * HD;
            kf[cg][0] = *(const short8*)(kr + grp * 8);
            kf[cg][1] = *(const short8*)(kr + 32 + grp * 8);
        }
#pragma unroll
        for (int dg = 0; dg < 4; ++dg) {
            const unsigned short* vr = Vg + (size_t)(dg * 16 + lm) * SEQ + kb;
            vf[dg][0] = *(const short8*)(vr + grp * 8);
            vf[dg][1] = *(const short8*)(vr + 32 + grp * 8);
        }

        // S^T = K Q^T per cg; softmax; pack P (wave-private LDS)
#pragma unroll
        for (int cg = 0; cg < 4; ++cg) {
            float4 mv = *(const float4*)&maskb[kb + cg * 16 + grp * 4];
            const float m0a = __builtin_fmaf(mv.x, BIGM, -BIGM);
            const float m1a = __builtin_fmaf(mv.y, BIGM, -BIGM);
            const float m2a = __builtin_fmaf(mv.z, BIGM, -BIGM);
            const float m3a = __builtin_fmaf(mv.w, BIGM, -BIGM);
#pragma unroll
            for (int qt = 0; qt < 4; ++qt) {
                floatx4 s = (floatx4){0.f, 0.f, 0.f, 0.f};
                s = __builtin_amdgcn_mfma_f32_16x16x32_bf16(kf[cg][0], qf[qt][0], s, 0, 0, 0);
                s = __builtin_amdgcn_mfma_f32_16x16x32_bf16(kf[cg][1], qf[qt][1], s, 0, 0, 0);
                float p0 = __builtin_exp2f(s[0] + m0a);
                float p1 = __builtin_exp2f(s[1] + m1a);
                float p2 = __builtin_exp2f(s[2] + m2a);
                float p3 = __builtin_exp2f(s[3] + m3a);
                lpart[qt] += (p0 + p1) + (p2 + p3);
                uint2 pk;
                pk.x = pk2r(p0, p1);
                pk.y = pk2r(p2, p3);
                *(uint2*)&Pw[(qt * 16 + lm) * 72 + cg * 16 + grp * 4] = pk;
            }
        }

        // O += P V  (A = P[m=q][k=key] via b128 LDS reads; B = V frags)
#pragma unroll
        for (int qt = 0; qt < 4; ++qt) {
            short8 ap0 = *(const short8*)&Pw[(qt * 16 + lm) * 72 + grp * 8];
            short8 ap1 = *(const short8*)&Pw[(qt * 16 + lm) * 72 + 32 + grp * 8];
#pragma unroll
            for (int dg = 0; dg < 4; ++dg) {
                oacc[qt][dg] = __builtin_amdgcn_mfma_f32_16x16x32_bf16(ap0, vf[dg][0], oacc[qt][dg], 0, 0, 0);
                oacc[qt][dg] = __builtin_amdgcn_mfma_f32_16x16x32_bf16(ap1, vf[dg][1], oacc[qt][dg], 0, 0, 0);
            }
        }
    }

    // ---- cross-wave reduction of key-partials ----
    // intra-wave l reduce: lanes {lm,+16,+32,+48} hold partials of q=qt*16+lm
    float lred[4];
#pragma unroll
    for (int qt = 0; qt < 4; ++qt) {
        float l = lpart[qt];
        l += __shfl_xor(l, 16);
        l += __shfl_xor(l, 32);
        lred[qt] = l;
    }

    __syncthreads();   // all waves done with their P tiles (union re-use)

    // wave w keeps tile qt==w in regs; exports tiles qt!=w
#pragma unroll
    for (int qt = 0; qt < 4; ++qt) {
        if (qt != w) {
            const int slot = qt * 3 + (w > qt ? w - 1 : w);
            float* T = sm.ep.Oex[slot];
#pragma unroll
            for (int dg = 0; dg < 4; ++dg)
#pragma unroll
                for (int r = 0; r < 4; ++r)
                    T[(grp * 4 + r) * 66 + dg * 16 + lm] = oacc[qt][dg][r];
        }
    }
    if (grp == 0) {
#pragma unroll
        for (int qt = 0; qt < 4; ++qt)
            sm.ep.Lex[w][qt * 16 + lm] = lred[qt];
    }
    __syncthreads();

    // wave w reduces + writes q-rows [q0 + w*16, q0 + w*16 + 16)
    float lt = sm.ep.Lex[0][w * 16 + lm] + sm.ep.Lex[1][w * 16 + lm]
             + sm.ep.Lex[2][w * 16 + lm] + sm.ep.Lex[3][w * 16 + lm];
    const float li = (lt > 0.f) ? 1.0f / lt : 0.f;
    float inv[4];
#pragma unroll
    for (int r = 0; r < 4; ++r) inv[r] = __shfl(li, grp * 4 + r);

#pragma unroll
    for (int qt = 0; qt < 4; ++qt) {
        if (qt == w) {
#pragma unroll
            for (int dg = 0; dg < 4; ++dg)
#pragma unroll
                for (int r = 0; r < 4; ++r) {
                    float v = oacc[qt][dg][r];
#pragma unroll
                    for (int j = 0; j < 3; ++j)
                        v += sm.ep.Oex[w * 3 + j][(grp * 4 + r) * 66 + dg * 16 + lm];
                    const int s = q0 + w * 16 + grp * 4 + r;
                    Cb[((size_t)(b * SEQ + s)) * DIM + h * HD + dg * 16 + lm] =
                        f2bf(v * inv[r]);
                }
        }
    }
}

// ---------------------------------------------------------------------------
// out = ctx @ Wo + bo  (128M x 64N tiles -> 512 blocks, fp32 out)
// ---------------------------------------------------------------------------
__global__ __launch_bounds__(256)
void out_gemm(const unsigned short* __restrict__ Cb,
              const unsigned short* __restrict__ Wto,
              const float* __restrict__ bo,
              float* __restrict__ out)
{
    __shared__ unsigned short As[128 * 32];
    __shared__ unsigned short Bs[64 * 32];

    const int t = threadIdx.x, w = t >> 6, lane = t & 63;
    const int lm = lane & 15, grp = lane >> 4;
    const int m0 = blockIdx.x * 128;
    const int n0 = blockIdx.y * 64;

    const int lr = lane >> 2, lc = (lane & 3) * 8;

    floatx4 acc[2][4];
#pragma unroll
    for (int i = 0; i < 2; ++i)
#pragma unroll
        for (int j = 0; j < 4; ++j) acc[i][j] = (floatx4){0.f, 0.f, 0.f, 0.f};

    for (int kt = 0; kt < DIM / 32; ++kt) {
        const int k0 = kt * 32;
        const int r0 = w * 16;
        gll16(Cb  + (size_t)(m0 + r0 + lr) * DIM + k0 + lc,      &As[r0 * 32]);
        gll16(Cb  + (size_t)(m0 + 64 + r0 + lr) * DIM + k0 + lc, &As[(64 + r0) * 32]);
        gll16(Wto + (size_t)(n0 + r0 + lr) * DIM + k0 + lc,      &Bs[r0 * 32]);
        __syncthreads();
        short8 af[2], bf[4];
#pragma unroll
        for (int mt = 0; mt < 2; ++mt)
            af[mt] = *(const short8*)&As[(w * 32 + mt * 16 + lm) * 32 + grp * 8];
#pragma unroll
        for (int nt = 0; nt < 4; ++nt)
            bf[nt] = *(const short8*)&Bs[(nt * 16 + lm) * 32 + grp * 8];
#pragma unroll
        for (int mt = 0; mt < 2; ++mt)
#pragma unroll
            for (int nt = 0; nt < 4; ++nt)
                acc[mt][nt] = __builtin_amdgcn_mfma_f32_16x16x32_bf16(af[mt], bf[nt], acc[mt][nt], 0, 0, 0);
        __syncthreads();
    }

#pragma unroll
    for (int nt = 0; nt < 4; ++nt) {
        const int c = n0 + nt * 16 + lm;
        const float bb = bo[c];
#pragma unroll
        for (int mt = 0; mt < 2; ++mt)
#pragma unroll
            for (int reg = 0; reg < 4; ++reg) {
                const int r = m0 + w * 32 + mt * 16 + grp * 4 + reg;
                out[(size_t)r * DIM + c] = acc[mt][nt][reg] + bb;
            }
    }
}

// ---------------------------------------------------------------------------
extern "C" void kernel_launch(void* const* d_in, const int* in_sizes, int n_in,
                              void* d_out, int out_size, void* d_ws, size_t ws_size,
                              hipStream_t stream)
{
    const float* x    = (const float*)d_in[0];
    const float* mask = (const float*)d_in[1];
    const float* Wq   = (const float*)d_in[2];
    const float* bq   = (const float*)d_in[3];
    const float* Wk   = (const float*)d_in[4];
    const float* bk   = (const float*)d_in[5];
    const float* Wv   = (const float*)d_in[6];
    const float* bv   = (const float*)d_in[7];
    const float* Wo   = (const float*)d_in[8];
    const float* bo   = (const float*)d_in[9];
    float* out = (float*)d_out;

    const size_t M1 = (size_t)DIM * DIM;           // 1M elems
    unsigned short* Qb  = (unsigned short*)d_ws;   // 4M elems each
    unsigned short* Kb  = Qb  + 4 * M1;
    unsigned short* VbT = Kb  + 4 * M1;
    unsigned short* Cb  = VbT + 4 * M1;
    unsigned short* Xbf = Cb  + 4 * M1;
    unsigned short* Wt3 = Xbf + 4 * M1;            // 3M elems
    unsigned short* Wto = Wt3 + 3 * M1;            // 1M elems  (48 MB total)

    conv_x <<<dim3((MTOT * DIM) / 2048), 256, 0, stream>>>(x, Xbf);
    conv_wt<<<dim3(16, 16, 4), 256, 0, stream>>>(Wq, Wk, Wv, Wo, Wt3, Wto);
    qkv_gemm<<<dim3(MTOT / 128, 24), 256, 0, stream>>>(Xbf, Wt3, bq, bk, bv, Qb, Kb, VbT);
    attn<<<dim3(SEQ / 64, BSZ * NHD), 256, 0, stream>>>(Qb, Kb, VbT, mask, Cb);
    out_gemm<<<dim3(MTOT / 128, DIM / 64), 256, 0, stream>>>(Cb, Wto, bo, out);
}